// Round 3
// baseline (1640.765 us; speedup 1.0000x reference)
//
#include <hip/hip_runtime.h>
#include <hip/hip_bf16.h>
#include <math.h>

#define N_ROWS 16384
#define DIM    256
#define NE     8192
#define NSPLIT 4
#define BM 64
#define BN 64
#define BK 32

// ---- out layout (float indices) ----
// loss    @ 0
// z_q_st  @ 1          (4194304)
// perp    @ 4194305
// one_hot @ 4194306    (134217728)   -> written LAST
// indices @ 138412034  (16384)       -> written as float by k_merge
//
// ---- scratch INSIDE the one_hot region (d_ws is never touched) ----
// S = 4194308 (16-byte aligned float offset into out)
// zf       @ S+0        (4194304 f32)  z as (N,D)
// esq      @ S+4194304  (8192)
// zsq      @ S+4202496  (16384)
// rb_d     @ S+4218880  (65536)
// rb_j     @ S+4284416  (65536, int)
// losspart @ S+4349952  (16384)
// scratch ends at S+4366336 = out[8560644] << one_hot end 138412034.
// All scratch consumers run BEFORE k_onehot overwrites the region.
#define SOFF 4194308

// ---------- kernel 1: transpose z (B,C,H,W) -> zf (N=B*H*W, C) ----------
__global__ void k_transpose_z(const float* __restrict__ z, float* __restrict__ zf) {
  __shared__ float tile[32][33];
  int ct = blockIdx.x;        // 8 c-tiles
  int ht = blockIdx.y;        // 32 hw-tiles
  int b  = blockIdx.z;        // 16
  int tx = threadIdx.x & 31;
  int ty = threadIdx.x >> 5;  // 0..7
  int c0 = ct * 32, hw0 = ht * 32;
  const size_t zb = (size_t)b * 256 * 1024;
#pragma unroll
  for (int p = 0; p < 4; ++p) {
    int c = p * 8 + ty;
    tile[c][tx] = z[zb + (size_t)(c0 + c) * 1024 + hw0 + tx];
  }
  __syncthreads();
#pragma unroll
  for (int p = 0; p < 4; ++p) {
    int r = p * 8 + ty;  // local hw
    zf[(size_t)(b * 1024 + hw0 + r) * DIM + c0 + tx] = tile[tx][r];
  }
}

// ---------- kernel 2: numpy-pairwise-exact sum of squares ----------
__device__ __forceinline__ float np_sumsq_128(const float* __restrict__ p) {
  float r[8];
#pragma unroll
  for (int j = 0; j < 8; ++j) r[j] = __fmul_rn(p[j], p[j]);
  for (int i = 8; i < 128; i += 8) {
#pragma unroll
    for (int j = 0; j < 8; ++j) r[j] = __fadd_rn(r[j], __fmul_rn(p[i + j], p[i + j]));
  }
  return __fadd_rn(__fadd_rn(__fadd_rn(r[0], r[1]), __fadd_rn(r[2], r[3])),
                   __fadd_rn(__fadd_rn(r[4], r[5]), __fadd_rn(r[6], r[7])));
}

__global__ void k_sumsq(const float* __restrict__ ew, const float* __restrict__ zf,
                        float* __restrict__ esq, float* __restrict__ zsq) {
  int t = blockIdx.x * blockDim.x + threadIdx.x;  // 0..24575
  if (t < NE) {
    const float* p = ew + (size_t)t * DIM;
    esq[t] = __fadd_rn(np_sumsq_128(p), np_sumsq_128(p + 128));
  } else {
    int r = t - NE;
    const float* p = zf + (size_t)r * DIM;
    zsq[r] = __fadd_rn(np_sumsq_128(p), np_sumsq_128(p + 128));
  }
}

// ---------- kernel 3: fp32 tiled GEMM (scores) + fused argmin ----------
__global__ __launch_bounds__(256) void k_gemm_argmin(
    const float* __restrict__ zf, const float* __restrict__ ew,
    const float* __restrict__ zsq, const float* __restrict__ esq,
    float* __restrict__ rb_d, int* __restrict__ rb_j) {
  __shared__ __align__(16) float As[BK][BM + 4];
  __shared__ __align__(16) float Bs[BK][BN + 4];
  const int tid = threadIdx.x;
  const int tx = tid & 15, ty = tid >> 4;
  const int row0  = blockIdx.x * BM;
  const int code0 = blockIdx.y * (NE / NSPLIT);

  float bestd[4]; int bestj[4];
#pragma unroll
  for (int i = 0; i < 4; ++i) { bestd[i] = INFINITY; bestj[i] = 0; }
  float zs[4];
#pragma unroll
  for (int i = 0; i < 4; ++i) zs[i] = zsq[row0 + ty * 4 + i];

  for (int ct = 0; ct < (NE / NSPLIT) / BN; ++ct) {
    const int c0 = code0 + ct * BN;
    float acc[4][4];
#pragma unroll
    for (int i = 0; i < 4; ++i)
#pragma unroll
      for (int j = 0; j < 4; ++j) acc[i][j] = 0.f;

    for (int kt = 0; kt < DIM / BK; ++kt) {
      const int k0 = kt * BK;
      __syncthreads();
#pragma unroll
      for (int u = 0; u < 2; ++u) {
        int t2 = tid * 2 + u;          // 0..511
        int r  = t2 >> 3;              // 0..63
        int kq = (t2 & 7) * 4;         // 0..28
        float4 av = *reinterpret_cast<const float4*>(zf + (size_t)(row0 + r) * DIM + k0 + kq);
        As[kq + 0][r] = av.x; As[kq + 1][r] = av.y; As[kq + 2][r] = av.z; As[kq + 3][r] = av.w;
        float4 bv = *reinterpret_cast<const float4*>(ew + (size_t)(c0 + r) * DIM + k0 + kq);
        Bs[kq + 0][r] = bv.x; Bs[kq + 1][r] = bv.y; Bs[kq + 2][r] = bv.z; Bs[kq + 3][r] = bv.w;
      }
      __syncthreads();
#pragma unroll 8
      for (int k = 0; k < BK; ++k) {
        float4 a = *reinterpret_cast<const float4*>(&As[k][ty * 4]);
        float4 b = *reinterpret_cast<const float4*>(&Bs[k][tx * 4]);
        acc[0][0] += a.x * b.x; acc[0][1] += a.x * b.y; acc[0][2] += a.x * b.z; acc[0][3] += a.x * b.w;
        acc[1][0] += a.y * b.x; acc[1][1] += a.y * b.y; acc[1][2] += a.y * b.z; acc[1][3] += a.y * b.w;
        acc[2][0] += a.z * b.x; acc[2][1] += a.z * b.y; acc[2][2] += a.z * b.z; acc[2][3] += a.z * b.w;
        acc[3][0] += a.w * b.x; acc[3][1] += a.w * b.y; acc[3][2] += a.w * b.z; acc[3][3] += a.w * b.w;
      }
    }
    // epilogue: d = fl(fl(zsq+esq) - fl(2*dot)), first-index tie-break
#pragma unroll
    for (int i = 0; i < 4; ++i) {
#pragma unroll
      for (int jj = 0; jj < 4; ++jj) {
        int j = c0 + tx * 4 + jj;
        float d = __fsub_rn(__fadd_rn(zs[i], esq[j]), __fmul_rn(2.0f, acc[i][jj]));
        if (d < bestd[i] || (d == bestd[i] && j < bestj[i])) { bestd[i] = d; bestj[i] = j; }
      }
    }
  }
  // lexicographic (d, j) min across the 16 lanes sharing a row-group
#pragma unroll
  for (int off = 1; off < 16; off <<= 1) {
#pragma unroll
    for (int i = 0; i < 4; ++i) {
      float od = __shfl_xor(bestd[i], off, 64);
      int   oj = __shfl_xor(bestj[i], off, 64);
      if (od < bestd[i] || (od == bestd[i] && oj < bestj[i])) { bestd[i] = od; bestj[i] = oj; }
    }
  }
  if (tx == 0) {
#pragma unroll
    for (int i = 0; i < 4; ++i) {
      int r = row0 + ty * 4 + i;
      rb_d[blockIdx.y * N_ROWS + r] = bestd[i];
      rb_j[blockIdx.y * N_ROWS + r] = bestj[i];
    }
  }
}

// ---------- kernel 4: merge splits -> indices (float) + per-row loss partial ----------
__global__ void k_merge(const float* __restrict__ rb_d, const int* __restrict__ rb_j,
                        const float* __restrict__ zf, const float* __restrict__ ew,
                        float* __restrict__ losspart, float* __restrict__ out_idx) {
  int row  = blockIdx.x * 4 + (threadIdx.x >> 6);
  int lane = threadIdx.x & 63;
  float bd = rb_d[row]; int bj = rb_j[row];
#pragma unroll
  for (int s = 1; s < NSPLIT; ++s) {
    float d = rb_d[s * N_ROWS + row]; int j = rb_j[s * N_ROWS + row];
    if (d < bd || (d == bd && j < bj)) { bd = d; bj = j; }
  }
  int c = lane * 4;
  float4 e4 = *reinterpret_cast<const float4*>(ew + (size_t)bj * DIM + c);
  float4 z4 = *reinterpret_cast<const float4*>(zf + (size_t)row * DIM + c);
  float t0 = __fsub_rn(e4.x, z4.x), t1 = __fsub_rn(e4.y, z4.y);
  float t2 = __fsub_rn(e4.z, z4.z), t3 = __fsub_rn(e4.w, z4.w);
  float s = __fadd_rn(__fadd_rn(__fmul_rn(t0, t0), __fmul_rn(t1, t1)),
                      __fadd_rn(__fmul_rn(t2, t2), __fmul_rn(t3, t3)));
#pragma unroll
  for (int off = 1; off < 64; off <<= 1) s += __shfl_xor(s, off, 64);
  if (lane == 0) {
    out_idx[row] = (float)bj;   // <=8191, exact in fp32
    losspart[row] = s;
  }
}

// ---------- kernel 5: z_q_st = fl(z + fl(e_w[idx] - z)), back to (B,C,H,W) ----------
__global__ void k_zq_out(const float* __restrict__ z, const float* __restrict__ ew,
                         const float* __restrict__ idxF, float* __restrict__ out) {
  __shared__ float tileE[32][33];
  __shared__ int sidx[32];
  int ct = blockIdx.x;  // 8
  int ht = blockIdx.y;  // 32
  int b  = blockIdx.z;  // 16
  int tx = threadIdx.x & 31, ty = threadIdx.x >> 5;
  int c0 = ct * 32, hw0 = ht * 32;
  if (threadIdx.x < 32) sidx[threadIdx.x] = (int)idxF[b * 1024 + hw0 + threadIdx.x];
  __syncthreads();
#pragma unroll
  for (int p = 0; p < 4; ++p) {
    int r = p * 8 + ty;
    tileE[tx][r] = ew[(size_t)sidx[r] * DIM + c0 + tx];
  }
  __syncthreads();
  float* outq = out + 1;
#pragma unroll
  for (int p = 0; p < 4; ++p) {
    int cl = p * 8 + ty;
    size_t gi = (size_t)(b * 256 + c0 + cl) * 1024 + hw0 + tx;
    float zv = z[gi];
    float e  = tileE[cl][tx];
    outq[gi] = __fadd_rn(zv, __fsub_rn(e, zv));
  }
}

// ---------- kernel 6: loss + perplexity (single block, LDS histogram) ----------
__global__ __launch_bounds__(256) void k_scalars(const float* __restrict__ idxF,
                                                 const float* __restrict__ losspart,
                                                 float* __restrict__ out) {
  __shared__ int hist[NE];          // 32 KB
  __shared__ float red[256];
  int t = threadIdx.x;
  for (int i = t; i < NE; i += 256) hist[i] = 0;
  __syncthreads();
  float ls = 0.f;
  for (int i = t; i < N_ROWS; i += 256) {
    atomicAdd(&hist[(int)idxF[i]], 1);
    ls += losspart[i];
  }
  __syncthreads();
  float es = 0.f;
  for (int i = t; i < NE; i += 256) {
    float p = (float)hist[i] * (1.0f / 16384.0f);
    es += p * logf(p + 1e-10f);
  }
  red[t] = es; __syncthreads();
  for (int w = 128; w > 0; w >>= 1) { if (t < w) red[t] += red[t + w]; __syncthreads(); }
  float esum = red[0]; __syncthreads();
  red[t] = ls; __syncthreads();
  for (int w = 128; w > 0; w >>= 1) { if (t < w) red[t] += red[t + w]; __syncthreads(); }
  if (t == 0) {
    out[4194305] = expf(-esum);
    float m = red[0] * (1.0f / 4194304.0f);       // exact pow2 divide
    out[0] = __fadd_rn(m, __fmul_rn(0.25f, m));   // loss_embed + 0.25*loss_commit
  }
}

// ---------- kernel 7 (LAST): one_hot (537 MB, float2 stores) ----------
__global__ void k_onehot(const float* __restrict__ idxF, float* __restrict__ out) {
  int row  = blockIdx.x * 4 + (threadIdx.x >> 6);
  int lane = threadIdx.x & 63;
  int idx = (int)idxF[row];
  float2* o2 = reinterpret_cast<float2*>(out + 4194306 + (size_t)row * NE);
#pragma unroll 8
  for (int i = 0; i < 64; ++i) {
    int j0 = i * 128 + lane * 2;
    float2 v;
    v.x = (j0     == idx) ? 1.0f : 0.0f;
    v.y = (j0 + 1 == idx) ? 1.0f : 0.0f;
    o2[j0 >> 1] = v;
  }
}

extern "C" void kernel_launch(void* const* d_in, const int* in_sizes, int n_in,
                              void* d_out, int out_size, void* d_ws, size_t ws_size,
                              hipStream_t stream) {
  const float* z  = (const float*)d_in[0];
  const float* ew = (const float*)d_in[1];
  float* out = (float*)d_out;
  // scratch lives inside the one_hot output region (overwritten last)
  float* zf   = out + SOFF;
  float* esq  = out + SOFF + 4194304;
  float* zsq  = out + SOFF + 4202496;
  float* rb_d = out + SOFF + 4218880;
  int*   rb_j = (int*)(out + SOFF + 4284416);
  float* lprt = out + SOFF + 4349952;
  float* idxF = out + 138412034;

  k_transpose_z<<<dim3(8, 32, 16), 256, 0, stream>>>(z, zf);
  k_sumsq<<<dim3(96), 256, 0, stream>>>(ew, zf, esq, zsq);
  k_gemm_argmin<<<dim3(256, NSPLIT), 256, 0, stream>>>(zf, ew, zsq, esq, rb_d, rb_j);
  k_merge<<<dim3(4096), 256, 0, stream>>>(rb_d, rb_j, zf, ew, lprt, idxF);
  k_zq_out<<<dim3(8, 32, 16), 256, 0, stream>>>(z, ew, idxF, out);
  k_scalars<<<1, 256, 0, stream>>>(idxF, lprt, out);
  k_onehot<<<dim3(4096), 256, 0, stream>>>(idxF, out);
}

// Round 4
// 1200.841 us; speedup vs baseline: 1.3663x; 1.3663x over previous
//
#include <hip/hip_runtime.h>
#include <hip/hip_bf16.h>
#include <math.h>

#define N_ROWS 16384
#define DIM    256
#define NE     8192
#define EPS    1.5e-4f

// ---- out layout (float indices) ----
// loss @0 | z_q_st @1 (4194304) | perp @4194305 | one_hot @4194306 (134217728)
// indices @138412034 (16384)
//
// ---- scratch INSIDE one_hot region (d_ws untouched), 16B-aligned base ----
// SOFF = 4194308 (byte-16-aligned float offset)
// zf       @ SOFF+0         (4194304 f32)  z as (N,D)
// part     @ SOFF+4194304   (16777216 f32) 16384 rows x 64 blk x 4 sub x (s1,j1,s2,j2)
// losspart @ SOFF+20971520  (16384 f32)
// ends @ out[25182212] << one_hot end 138412034; k_onehot overwrites last.
#define SOFF 4194308

typedef __bf16 bf16x8 __attribute__((ext_vector_type(8)));
typedef float  f32x4  __attribute__((ext_vector_type(4)));

// ---------- kernel 1: transpose z (B,C,H,W) -> zf (N, C) ----------
__global__ void k_transpose_z(const float* __restrict__ z, float* __restrict__ zf) {
  __shared__ float tile[32][33];
  int ct = blockIdx.x, ht = blockIdx.y, b = blockIdx.z;
  int tx = threadIdx.x & 31, ty = threadIdx.x >> 5;
  int c0 = ct * 32, hw0 = ht * 32;
  const size_t zb = (size_t)b * 256 * 1024;
#pragma unroll
  for (int p = 0; p < 4; ++p) {
    int c = p * 8 + ty;
    tile[c][tx] = z[zb + (size_t)(c0 + c) * 1024 + hw0 + tx];
  }
  __syncthreads();
#pragma unroll
  for (int p = 0; p < 4; ++p) {
    int r = p * 8 + ty;
    zf[(size_t)(b * 1024 + hw0 + r) * DIM + c0 + tx] = tile[tx][r];
  }
}

// ---------- numpy-pairwise-exact sum of squares over 128 ----------
__device__ __forceinline__ float np_sumsq_128(const float* __restrict__ p) {
  float r[8];
#pragma unroll
  for (int j = 0; j < 8; ++j) r[j] = __fmul_rn(p[j], p[j]);
  for (int i = 8; i < 128; i += 8) {
#pragma unroll
    for (int j = 0; j < 8; ++j) r[j] = __fadd_rn(r[j], __fmul_rn(p[i + j], p[i + j]));
  }
  return __fadd_rn(__fadd_rn(__fadd_rn(r[0], r[1]), __fadd_rn(r[2], r[3])),
                   __fadd_rn(__fadd_rn(r[4], r[5]), __fadd_rn(r[6], r[7])));
}

// ---------- kernel 2: bf16 MFMA scores + per-(row,blk,32-sub) top-2 ----------
// s~ = -2*dot_bf16 (esq omitted: its spread ~1e-6 << EPS). 128x128 tile/block,
// 4 waves 2x2, 16x16x32 MFMA, fragment-order LDS (conflict-floor reads).
__global__ __launch_bounds__(256) void k_score(const float* __restrict__ zf,
                                               const float* __restrict__ ew,
                                               float* __restrict__ part) {
  __shared__ __align__(16) __bf16 As[4096];  // 8 tiles x 64 lanes x 8
  __shared__ __align__(16) __bf16 Bs[4096];
  const int tid = threadIdx.x;
  const int lane = tid & 63, wave = tid >> 6;
  const int wm = wave >> 1, wn = wave & 1;
  const int quad = lane >> 4, l15 = lane & 15;
  const int row0 = blockIdx.x * 128;
  const int by = blockIdx.y;
  const int col0 = by * 128;

  f32x4 acc[4][4];
#pragma unroll
  for (int i = 0; i < 4; ++i)
#pragma unroll
    for (int j = 0; j < 4; ++j) acc[i][j] = (f32x4){0.f, 0.f, 0.f, 0.f};

  for (int kt = 0; kt < 8; ++kt) {
    const int k0 = kt * 32;
    __syncthreads();
#pragma unroll
    for (int u = 0; u < 2; ++u) {
      int cid = tid * 2 + u;            // 0..511
      int m = cid >> 2, kc = cid & 3;   // row-in-tile, 8-elem k-chunk
      int slot = (m >> 4) * 512 + (kc * 16 + (m & 15)) * 8;  // fragment order
      {
        const float* s = zf + (size_t)(row0 + m) * DIM + k0 + kc * 8;
        float4 a0 = *(const float4*)s, a1 = *(const float4*)(s + 4);
        bf16x8 v = {(__bf16)a0.x, (__bf16)a0.y, (__bf16)a0.z, (__bf16)a0.w,
                    (__bf16)a1.x, (__bf16)a1.y, (__bf16)a1.z, (__bf16)a1.w};
        *(bf16x8*)(As + slot) = v;
      }
      {
        const float* s = ew + (size_t)(col0 + m) * DIM + k0 + kc * 8;
        float4 b0 = *(const float4*)s, b1 = *(const float4*)(s + 4);
        bf16x8 v = {(__bf16)b0.x, (__bf16)b0.y, (__bf16)b0.z, (__bf16)b0.w,
                    (__bf16)b1.x, (__bf16)b1.y, (__bf16)b1.z, (__bf16)b1.w};
        *(bf16x8*)(Bs + slot) = v;
      }
    }
    __syncthreads();
    bf16x8 af[4], bfr[4];
#pragma unroll
    for (int mi = 0; mi < 4; ++mi)
      af[mi] = *(bf16x8*)(As + (wm * 4 + mi) * 512 + lane * 8);
#pragma unroll
    for (int ni = 0; ni < 4; ++ni)
      bfr[ni] = *(bf16x8*)(Bs + (wn * 4 + ni) * 512 + lane * 8);
#pragma unroll
    for (int mi = 0; mi < 4; ++mi)
#pragma unroll
      for (int ni = 0; ni < 4; ++ni)
        acc[mi][ni] = __builtin_amdgcn_mfma_f32_16x16x32_bf16(af[mi], bfr[ni],
                                                              acc[mi][ni], 0, 0, 0);
  }

  // epilogue: per row, top-2 of each 32-col subgroup (lex on (s,j))
  const int colb = col0 + wn * 64;
#pragma unroll
  for (int mi = 0; mi < 4; ++mi) {
#pragma unroll
    for (int rg = 0; rg < 4; ++rg) {
      int row = row0 + wm * 64 + mi * 16 + quad * 4 + rg;
      float sA1, sA2, sB1, sB2; int jA1, jA2, jB1, jB2;
      {
        float v0 = -2.f * acc[mi][0][rg]; int j0 = colb + l15;
        float v1 = -2.f * acc[mi][1][rg]; int j1 = colb + 16 + l15;
        bool lt = (v0 < v1);
        sA1 = lt ? v0 : v1; jA1 = lt ? j0 : j1;
        sA2 = lt ? v1 : v0; jA2 = lt ? j1 : j0;
      }
      {
        float v0 = -2.f * acc[mi][2][rg]; int j0 = colb + 32 + l15;
        float v1 = -2.f * acc[mi][3][rg]; int j1 = colb + 48 + l15;
        bool lt = (v0 < v1);
        sB1 = lt ? v0 : v1; jB1 = lt ? j0 : j1;
        sB2 = lt ? v1 : v0; jB2 = lt ? j1 : j0;
      }
#pragma unroll
      for (int d = 1; d < 16; d <<= 1) {
        {
          float o1 = __shfl_xor(sA1, d), o2 = __shfl_xor(sA2, d);
          int oj1 = __shfl_xor(jA1, d), oj2 = __shfl_xor(jA2, d);
          bool lt1 = (o1 < sA1) || (o1 == sA1 && oj1 < jA1);
          float n1 = lt1 ? o1 : sA1; int nj1 = lt1 ? oj1 : jA1;
          float x1 = lt1 ? sA1 : o1; int xj1 = lt1 ? jA1 : oj1;
          bool lt2 = (o2 < sA2) || (o2 == sA2 && oj2 < jA2);
          float y1 = lt2 ? o2 : sA2; int yj1 = lt2 ? oj2 : jA2;
          bool lt3 = (x1 < y1) || (x1 == y1 && xj1 < yj1);
          sA1 = n1; jA1 = nj1;
          sA2 = lt3 ? x1 : y1; jA2 = lt3 ? xj1 : yj1;
        }
        {
          float o1 = __shfl_xor(sB1, d), o2 = __shfl_xor(sB2, d);
          int oj1 = __shfl_xor(jB1, d), oj2 = __shfl_xor(jB2, d);
          bool lt1 = (o1 < sB1) || (o1 == sB1 && oj1 < jB1);
          float n1 = lt1 ? o1 : sB1; int nj1 = lt1 ? oj1 : jB1;
          float x1 = lt1 ? sB1 : o1; int xj1 = lt1 ? jB1 : oj1;
          bool lt2 = (o2 < sB2) || (o2 == sB2 && oj2 < jB2);
          float y1 = lt2 ? o2 : sB2; int yj1 = lt2 ? oj2 : jB2;
          bool lt3 = (x1 < y1) || (x1 == y1 && xj1 < yj1);
          sB1 = n1; jB1 = nj1;
          sB2 = lt3 ? x1 : y1; jB2 = lt3 ? xj1 : yj1;
        }
      }
      if (l15 == 0) {
        float4* p4 = (float4*)part;
        int base = ((row * 64) + by) * 4 + wn * 2;
        p4[base]     = (float4){sA1, __int_as_float(jA1), sA2, __int_as_float(jA2)};
        p4[base + 1] = (float4){sB1, __int_as_float(jB1), sB2, __int_as_float(jB2)};
      }
    }
  }
}

// ---------- kernel 3: per-row candidate filter + exact fp32 rescore ----------
__global__ __launch_bounds__(256) void k_pick(const float* __restrict__ part,
                                              const float* __restrict__ zf,
                                              const float* __restrict__ ew,
                                              float* __restrict__ idxF,
                                              float* __restrict__ losspart) {
  __shared__ float smin[4];
  __shared__ int scnt, sbj;
  __shared__ int cand[64];
  __shared__ float cd[64]; __shared__ int cj[64];
  __shared__ float red[256];
  const int r = blockIdx.x, t = threadIdx.x;
  const int lane = t & 63, wv = t >> 6;
  if (t == 0) scnt = 0;
  const float4 pv = ((const float4*)part)[r * 256 + t];  // (s1,j1,s2,j2), s1<=s2
  float lmin = pv.x;
#pragma unroll
  for (int d = 1; d < 64; d <<= 1) lmin = fminf(lmin, __shfl_xor(lmin, d));
  if (lane == 0) smin[wv] = lmin;
  __syncthreads();
  const float gthr = fminf(fminf(smin[0], smin[1]), fminf(smin[2], smin[3])) + EPS;
  if (pv.x <= gthr) { int p = atomicAdd(&scnt, 1); if (p < 64) cand[p] = __float_as_int(pv.y); }
  if (pv.z <= gthr) { int p = atomicAdd(&scnt, 1); if (p < 64) cand[p] = __float_as_int(pv.w); }
  __syncthreads();
  const int cnt = min(scnt, 64);
  const float* zr = zf + (size_t)r * DIM;
  for (int i = t; i < cnt; i += 256) {
    int j = cand[i];
    const float* e = ew + (size_t)j * DIM;
    float acc = 0.f;
    for (int k = 0; k < DIM; ++k) acc = __builtin_fmaf(zr[k], e[k], acc);  // round-3 order
    float esq = __fadd_rn(np_sumsq_128(e), np_sumsq_128(e + 128));
    float zsq = __fadd_rn(np_sumsq_128(zr), np_sumsq_128(zr + 128));
    cd[i] = __fsub_rn(__fadd_rn(zsq, esq), __fmul_rn(2.0f, acc));
    cj[i] = j;
  }
  __syncthreads();
  if (t == 0) {
    float bd = cd[0]; int bj = cj[0];
    for (int i = 1; i < cnt; ++i) {
      if (cd[i] < bd || (cd[i] == bd && cj[i] < bj)) { bd = cd[i]; bj = cj[i]; }
    }
    idxF[r] = (float)bj;
    sbj = bj;
  }
  __syncthreads();
  float df = __fsub_rn(ew[(size_t)sbj * DIM + t], zr[t]);
  red[t] = __fmul_rn(df, df);
  __syncthreads();
  for (int w = 128; w > 0; w >>= 1) { if (t < w) red[t] += red[t + w]; __syncthreads(); }
  if (t == 0) losspart[r] = red[0];
}

// ---------- kernel 4: loss + perplexity (single block, LDS histogram) ----------
__global__ __launch_bounds__(256) void k_scalars(const float* __restrict__ idxF,
                                                 const float* __restrict__ losspart,
                                                 float* __restrict__ out) {
  __shared__ int hist[NE];
  __shared__ float red[256];
  int t = threadIdx.x;
  for (int i = t; i < NE; i += 256) hist[i] = 0;
  __syncthreads();
  float ls = 0.f;
  for (int i = t; i < N_ROWS; i += 256) {
    atomicAdd(&hist[(int)idxF[i]], 1);
    ls += losspart[i];
  }
  __syncthreads();
  float es = 0.f;
  for (int i = t; i < NE; i += 256) {
    float p = (float)hist[i] * (1.0f / 16384.0f);
    es += p * logf(p + 1e-10f);
  }
  red[t] = es; __syncthreads();
  for (int w = 128; w > 0; w >>= 1) { if (t < w) red[t] += red[t + w]; __syncthreads(); }
  float esum = red[0]; __syncthreads();
  red[t] = ls; __syncthreads();
  for (int w = 128; w > 0; w >>= 1) { if (t < w) red[t] += red[t + w]; __syncthreads(); }
  if (t == 0) {
    out[4194305] = expf(-esum);
    float m = red[0] * (1.0f / 4194304.0f);
    out[0] = __fadd_rn(m, __fmul_rn(0.25f, m));
  }
}

// ---------- kernel 5: z_q_st back to (B,C,H,W) ----------
__global__ void k_zq_out(const float* __restrict__ z, const float* __restrict__ ew,
                         const float* __restrict__ idxF, float* __restrict__ out) {
  __shared__ float tileE[32][33];
  __shared__ int sidx[32];
  int ct = blockIdx.x, ht = blockIdx.y, b = blockIdx.z;
  int tx = threadIdx.x & 31, ty = threadIdx.x >> 5;
  int c0 = ct * 32, hw0 = ht * 32;
  if (threadIdx.x < 32) sidx[threadIdx.x] = (int)idxF[b * 1024 + hw0 + threadIdx.x];
  __syncthreads();
#pragma unroll
  for (int p = 0; p < 4; ++p) {
    int r = p * 8 + ty;
    tileE[tx][r] = ew[(size_t)sidx[r] * DIM + c0 + tx];
  }
  __syncthreads();
  float* outq = out + 1;
#pragma unroll
  for (int p = 0; p < 4; ++p) {
    int cl = p * 8 + ty;
    size_t gi = (size_t)(b * 256 + c0 + cl) * 1024 + hw0 + tx;
    float zv = z[gi];
    outq[gi] = __fadd_rn(zv, __fsub_rn(tileE[cl][tx], zv));
  }
}

// ---------- kernel 6 (LAST): one_hot, overwrites scratch ----------
__global__ void k_onehot(const float* __restrict__ idxF, float* __restrict__ out) {
  int row  = blockIdx.x * 4 + (threadIdx.x >> 6);
  int lane = threadIdx.x & 63;
  int idx = (int)idxF[row];
  float2* o2 = reinterpret_cast<float2*>(out + 4194306 + (size_t)row * NE);
#pragma unroll 8
  for (int i = 0; i < 64; ++i) {
    int j0 = i * 128 + lane * 2;
    float2 v;
    v.x = (j0     == idx) ? 1.0f : 0.0f;
    v.y = (j0 + 1 == idx) ? 1.0f : 0.0f;
    o2[j0 >> 1] = v;
  }
}

extern "C" void kernel_launch(void* const* d_in, const int* in_sizes, int n_in,
                              void* d_out, int out_size, void* d_ws, size_t ws_size,
                              hipStream_t stream) {
  const float* z  = (const float*)d_in[0];
  const float* ew = (const float*)d_in[1];
  float* out = (float*)d_out;
  float* zf   = out + SOFF;
  float* part = out + SOFF + 4194304;
  float* lprt = out + SOFF + 20971520;
  float* idxF = out + 138412034;

  k_transpose_z<<<dim3(8, 32, 16), 256, 0, stream>>>(z, zf);
  k_score<<<dim3(128, 64), 256, 0, stream>>>(zf, ew, part);
  k_pick<<<dim3(16384), 256, 0, stream>>>(part, zf, ew, idxF, lprt);
  k_scalars<<<1, 256, 0, stream>>>(idxF, lprt, out);
  k_zq_out<<<dim3(8, 32, 16), 256, 0, stream>>>(z, ew, idxF, out);
  k_onehot<<<dim3(4096), 256, 0, stream>>>(idxF, out);
}

// Round 6
// 1074.458 us; speedup vs baseline: 1.5271x; 1.1176x over previous
//
#include <hip/hip_runtime.h>
#include <hip/hip_bf16.h>
#include <math.h>

#define N_ROWS 16384
#define DIM    256
#define NE     8192
#define QMARGIN 21   // ceil(eps/step)+1, step=2^-17, eps~1.5e-4

// ---- out layout (float indices) ----
// loss @0 | z_q_st @1 (4194304) | perp @4194305 | one_hot @4194306 (134217728)
// indices @138412034 (16384)
//
// ---- scratch INSIDE one_hot region (d_ws untouched), 16B-aligned ----
// SOFF = 4194308
// zf    @ SOFF+0         (4194304 f32)   z as (N,D)
// zfb   @ SOFF+4194304   (4194304 bf16)  fragment-order bf16 z
// ewb   @ SOFF+6291456   (2097152 bf16)  fragment-order bf16 codebook
// part  @ SOFF+7340032   (8388608 i32)   per (row,128colblk): 4 subs x top2 keys
// lprt  @ SOFF+15728640  (16384 f32)
// ends @ out[19939332] << 138412034; k_onehot overwrites last.
#define SOFF 4194308

typedef __bf16 bf16x8 __attribute__((ext_vector_type(8)));
typedef float  f32x4  __attribute__((ext_vector_type(4)));
typedef float  vf4    __attribute__((ext_vector_type(4)));

__device__ __forceinline__ void gload_lds16(const __bf16* g, __bf16* l) {
  __builtin_amdgcn_global_load_lds(
      (const __attribute__((address_space(1))) unsigned int*)g,
      (__attribute__((address_space(3))) unsigned int*)l, 16, 0, 0);
}

// ---------- kernel 1: transpose z (B,C,H,W) -> zf (N, C) ----------
__global__ void k_transpose_z(const float* __restrict__ z, float* __restrict__ zf) {
  __shared__ float tile[32][33];
  int ct = blockIdx.x, ht = blockIdx.y, b = blockIdx.z;
  int tx = threadIdx.x & 31, ty = threadIdx.x >> 5;
  int c0 = ct * 32, hw0 = ht * 32;
  const size_t zb = (size_t)b * 256 * 1024;
#pragma unroll
  for (int p = 0; p < 4; ++p) {
    int c = p * 8 + ty;
    tile[c][tx] = z[zb + (size_t)(c0 + c) * 1024 + hw0 + tx];
  }
  __syncthreads();
#pragma unroll
  for (int p = 0; p < 4; ++p) {
    int r = p * 8 + ty;
    zf[(size_t)(b * 1024 + hw0 + r) * DIM + c0 + tx] = tile[tx][r];
  }
}

// ---------- kernel 2: fp32 -> bf16 in MFMA fragment order ----------
// layout: dst[t*32768 + kt*4096 + g*512 + (kc*16 + m15)*8 + j]
//   row = t*128 + g*16 + m15, k = kt*32 + kc*8 + j
__global__ void k_cvt(const float* __restrict__ zf, const float* __restrict__ ew,
                      __bf16* __restrict__ zfb, __bf16* __restrict__ ewb) {
  int gid = blockIdx.x * 256 + threadIdx.x;  // 0..786431
  int row = gid >> 5, kc8 = gid & 31;
  const float* src; __bf16* dst; int r;
  if (row < N_ROWS) { r = row; src = zf + (size_t)r * DIM + kc8 * 8; dst = zfb; }
  else { r = row - N_ROWS; src = ew + (size_t)r * DIM + kc8 * 8; dst = ewb; }
  float4 v0 = *(const float4*)src, v1 = *(const float4*)(src + 4);
  bf16x8 v = {(__bf16)v0.x, (__bf16)v0.y, (__bf16)v0.z, (__bf16)v0.w,
              (__bf16)v1.x, (__bf16)v1.y, (__bf16)v1.z, (__bf16)v1.w};
  int t = r >> 7, g = (r >> 4) & 7, m15 = r & 15, kt = kc8 >> 2, kc = kc8 & 3;
  *(bf16x8*)(dst + (size_t)t * 32768 + kt * 4096 + g * 512 + (kc * 16 + m15) * 8) = v;
}

// ---------- kernel 3: bf16 MFMA scores + packed-key top-2 per 32-sub ----------
__global__ __launch_bounds__(256) void k_score(const __bf16* __restrict__ zfb,
                                               const __bf16* __restrict__ ewb,
                                               int* __restrict__ part) {
  __shared__ __align__(16) __bf16 As[4096];
  __shared__ __align__(16) __bf16 Bs[4096];
  const int tid = threadIdx.x;
  const int lane = tid & 63, wave = tid >> 6;
  const int wm = wave >> 1, wn = wave & 1;
  const int quad = lane >> 4, l15 = lane & 15;
  const int bx = blockIdx.x, by = blockIdx.y;

  f32x4 acc[4][4];
#pragma unroll
  for (int i = 0; i < 4; ++i)
#pragma unroll
    for (int j = 0; j < 4; ++j) acc[i][j] = (f32x4){0.f, 0.f, 0.f, 0.f};

  const __bf16* Ag = zfb + (size_t)bx * 32768;
  const __bf16* Bg = ewb + (size_t)by * 32768;
  const int g0 = wave * 2;

  for (int kt = 0; kt < 8; ++kt) {
    __syncthreads();
    const __bf16* Ak = Ag + kt * 4096;
    const __bf16* Bk = Bg + kt * 4096;
    gload_lds16(Ak + g0 * 512 + lane * 8,       As + g0 * 512);
    gload_lds16(Ak + (g0 + 1) * 512 + lane * 8, As + (g0 + 1) * 512);
    gload_lds16(Bk + g0 * 512 + lane * 8,       Bs + g0 * 512);
    gload_lds16(Bk + (g0 + 1) * 512 + lane * 8, Bs + (g0 + 1) * 512);
    __syncthreads();
    bf16x8 af[4], bfr[4];
#pragma unroll
    for (int mi = 0; mi < 4; ++mi)
      af[mi] = *(const bf16x8*)(As + (wm * 4 + mi) * 512 + lane * 8);
#pragma unroll
    for (int ni = 0; ni < 4; ++ni)
      bfr[ni] = *(const bf16x8*)(Bs + (wn * 4 + ni) * 512 + lane * 8);
#pragma unroll
    for (int mi = 0; mi < 4; ++mi)
#pragma unroll
      for (int ni = 0; ni < 4; ++ni)
        acc[mi][ni] = __builtin_amdgcn_mfma_f32_16x16x32_bf16(af[mi], bfr[ni],
                                                              acc[mi][ni], 0, 0, 0);
  }

  // epilogue: key = (quant18(s) << 13) | col ; top-2 per 32-col subgroup
  const int colb = by * 128 + wn * 64;
#pragma unroll
  for (int mi = 0; mi < 4; ++mi) {
#pragma unroll
    for (int rg = 0; rg < 4; ++rg) {
      int row = bx * 128 + wm * 64 + mi * 16 + quad * 4 + rg;
      float sA0 = -2.f * acc[mi][0][rg], sA1 = -2.f * acc[mi][1][rg];
      float sB0 = -2.f * acc[mi][2][rg], sB1 = -2.f * acc[mi][3][rg];
      int qA0 = min(max((int)((sA0 + 1.0f) * 131072.0f), 0), 262143);
      int qA1 = min(max((int)((sA1 + 1.0f) * 131072.0f), 0), 262143);
      int qB0 = min(max((int)((sB0 + 1.0f) * 131072.0f), 0), 262143);
      int qB1 = min(max((int)((sB1 + 1.0f) * 131072.0f), 0), 262143);
      int kA0 = (qA0 << 13) | (colb + l15);
      int kA1 = (qA1 << 13) | (colb + 16 + l15);
      int kB0 = (qB0 << 13) | (colb + 32 + l15);
      int kB1 = (qB1 << 13) | (colb + 48 + l15);
      int a1 = min(kA0, kA1), a2 = max(kA0, kA1);
      int b1 = min(kB0, kB1), b2 = max(kB0, kB1);
#pragma unroll
      for (int d = 1; d < 16; d <<= 1) {
        int o1 = __shfl_xor(a1, d), o2 = __shfl_xor(a2, d);
        a2 = min(max(a1, o1), min(a2, o2));
        a1 = min(a1, o1);
        o1 = __shfl_xor(b1, d); o2 = __shfl_xor(b2, d);
        b2 = min(max(b1, o1), min(b2, o2));
        b1 = min(b1, o1);
      }
      if (l15 == 0)
        ((int4*)part)[((size_t)row * 64 + by) * 2 + wn] = (int4){a1, a2, b1, b2};
    }
  }
}

// ---------- numpy-pairwise-exact sum of squares over 128 ----------
__device__ __forceinline__ float np_sumsq_128(const float* __restrict__ p) {
  float r[8];
#pragma unroll
  for (int j = 0; j < 8; ++j) r[j] = __fmul_rn(p[j], p[j]);
  for (int i = 8; i < 128; i += 8) {
#pragma unroll
    for (int j = 0; j < 8; ++j) r[j] = __fadd_rn(r[j], __fmul_rn(p[i + j], p[i + j]));
  }
  return __fadd_rn(__fadd_rn(__fadd_rn(r[0], r[1]), __fadd_rn(r[2], r[3])),
                   __fadd_rn(__fadd_rn(r[4], r[5]), __fadd_rn(r[6], r[7])));
}

// ---------- kernel 4: candidate filter + exact fp32 rescore ----------
__global__ __launch_bounds__(256) void k_pick(const int* __restrict__ part,
                                              const float* __restrict__ zf,
                                              const float* __restrict__ ew,
                                              float* __restrict__ idxF,
                                              float* __restrict__ losspart) {
  __shared__ int smin[4];
  __shared__ int scnt, sbj;
  __shared__ int cand[64];
  __shared__ float cd[64]; __shared__ int cj[64];
  __shared__ float red[256];
  const int r = blockIdx.x, t = threadIdx.x;
  const int lane = t & 63, wv = t >> 6;
  if (t == 0) scnt = 0;
  const int2 pv = ((const int2*)part)[r * 256 + t];  // (k1,k2), k1<=k2
  int lmin = pv.x;
#pragma unroll
  for (int d = 1; d < 64; d <<= 1) lmin = min(lmin, __shfl_xor(lmin, d));
  if (lane == 0) smin[wv] = lmin;
  __syncthreads();
  const int kmin = min(min(smin[0], smin[1]), min(smin[2], smin[3]));
  const int qthr = min((kmin >> 13) + QMARGIN, 262143);
  const int kthr = (qthr << 13) | 8191;
  if (pv.x <= kthr) { int p = atomicAdd(&scnt, 1); if (p < 64) cand[p] = pv.x & 8191; }
  if (pv.y <= kthr) { int p = atomicAdd(&scnt, 1); if (p < 64) cand[p] = pv.y & 8191; }
  __syncthreads();
  const int cnt = min(scnt, 64);
  const float* zr = zf + (size_t)r * DIM;
  for (int i = t; i < cnt; i += 256) {
    int j = cand[i];
    const float* e = ew + (size_t)j * DIM;
    float acc = 0.f;
    for (int k = 0; k < DIM; ++k) acc = __builtin_fmaf(zr[k], e[k], acc);  // round-3 order
    float esq = __fadd_rn(np_sumsq_128(e), np_sumsq_128(e + 128));
    float zsq = __fadd_rn(np_sumsq_128(zr), np_sumsq_128(zr + 128));
    cd[i] = __fsub_rn(__fadd_rn(zsq, esq), __fmul_rn(2.0f, acc));
    cj[i] = j;
  }
  __syncthreads();
  if (t == 0) {
    float bd = cd[0]; int bj = cj[0];
    for (int i = 1; i < cnt; ++i) {
      if (cd[i] < bd || (cd[i] == bd && cj[i] < bj)) { bd = cd[i]; bj = cj[i]; }
    }
    idxF[r] = (float)bj;
    sbj = bj;
  }
  __syncthreads();
  float df = __fsub_rn(ew[(size_t)sbj * DIM + t], zr[t]);
  red[t] = __fmul_rn(df, df);
  __syncthreads();
  for (int w = 128; w > 0; w >>= 1) { if (t < w) red[t] += red[t + w]; __syncthreads(); }
  if (t == 0) losspart[r] = red[0];
}

// ---------- kernel 5: loss + perplexity ----------
__global__ __launch_bounds__(256) void k_scalars(const float* __restrict__ idxF,
                                                 const float* __restrict__ losspart,
                                                 float* __restrict__ out) {
  __shared__ int hist[NE];
  __shared__ float red[256];
  int t = threadIdx.x;
  for (int i = t; i < NE; i += 256) hist[i] = 0;
  __syncthreads();
  float ls = 0.f;
  for (int i = t; i < N_ROWS; i += 256) {
    atomicAdd(&hist[(int)idxF[i]], 1);
    ls += losspart[i];
  }
  __syncthreads();
  float es = 0.f;
  for (int i = t; i < NE; i += 256) {
    float p = (float)hist[i] * (1.0f / 16384.0f);
    es += p * logf(p + 1e-10f);
  }
  red[t] = es; __syncthreads();
  for (int w = 128; w > 0; w >>= 1) { if (t < w) red[t] += red[t + w]; __syncthreads(); }
  float esum = red[0]; __syncthreads();
  red[t] = ls; __syncthreads();
  for (int w = 128; w > 0; w >>= 1) { if (t < w) red[t] += red[t + w]; __syncthreads(); }
  if (t == 0) {
    out[4194305] = expf(-esum);
    float m = red[0] * (1.0f / 4194304.0f);
    out[0] = __fadd_rn(m, __fmul_rn(0.25f, m));
  }
}

// ---------- kernel 6: z_q_st back to (B,C,H,W) ----------
__global__ void k_zq_out(const float* __restrict__ z, const float* __restrict__ ew,
                         const float* __restrict__ idxF, float* __restrict__ out) {
  __shared__ float tileE[32][33];
  __shared__ int sidx[32];
  int ct = blockIdx.x, ht = blockIdx.y, b = blockIdx.z;
  int tx = threadIdx.x & 31, ty = threadIdx.x >> 5;
  int c0 = ct * 32, hw0 = ht * 32;
  if (threadIdx.x < 32) sidx[threadIdx.x] = (int)idxF[b * 1024 + hw0 + threadIdx.x];
  __syncthreads();
#pragma unroll
  for (int p = 0; p < 4; ++p) {
    int r = p * 8 + ty;
    tileE[tx][r] = ew[(size_t)sidx[r] * DIM + c0 + tx];
  }
  __syncthreads();
  float* outq = out + 1;
#pragma unroll
  for (int p = 0; p < 4; ++p) {
    int cl = p * 8 + ty;
    size_t gi = (size_t)(b * 256 + c0 + cl) * 1024 + hw0 + tx;
    float zv = z[gi];
    outq[gi] = __fadd_rn(zv, __fsub_rn(tileE[cl][tx], zv));
  }
}

// ---------- kernel 7 (LAST): one_hot, ext-vector NT stores ----------
__global__ void k_onehot(const float* __restrict__ idxF, float* __restrict__ out) {
  int row = blockIdx.x;
  int t = threadIdx.x;
  int idx = (int)idxF[row];
  float* p = out + 4194306 + (size_t)row * NE;
  if (t == 0) {
    float2 h; h.x = (0 == idx) ? 1.f : 0.f; h.y = (1 == idx) ? 1.f : 0.f;
    *(float2*)p = h;
    float2 q; q.x = (8190 == idx) ? 1.f : 0.f; q.y = (8191 == idx) ? 1.f : 0.f;
    *(float2*)(p + 8190) = q;
  }
  vf4* b4 = (vf4*)(p + 2);
#pragma unroll
  for (int it = 0; it < 8; ++it) {
    int i = it * 256 + t;
    if (i < 2047) {
      int c = 2 + i * 4;
      vf4 v;
      v.x = (c     == idx) ? 1.f : 0.f;
      v.y = (c + 1 == idx) ? 1.f : 0.f;
      v.z = (c + 2 == idx) ? 1.f : 0.f;
      v.w = (c + 3 == idx) ? 1.f : 0.f;
      __builtin_nontemporal_store(v, b4 + i);
    }
  }
}

extern "C" void kernel_launch(void* const* d_in, const int* in_sizes, int n_in,
                              void* d_out, int out_size, void* d_ws, size_t ws_size,
                              hipStream_t stream) {
  const float* z  = (const float*)d_in[0];
  const float* ew = (const float*)d_in[1];
  float* out = (float*)d_out;
  float*  zf   = out + SOFF;
  __bf16* zfb  = (__bf16*)(out + SOFF + 4194304);
  __bf16* ewb  = (__bf16*)(out + SOFF + 6291456);
  int*    part = (int*)(out + SOFF + 7340032);
  float*  lprt = out + SOFF + 15728640;
  float*  idxF = out + 138412034;

  k_transpose_z<<<dim3(8, 32, 16), 256, 0, stream>>>(z, zf);
  k_cvt<<<dim3(3072), 256, 0, stream>>>(zf, ew, zfb, ewb);
  k_score<<<dim3(128, 64), 256, 0, stream>>>(zfb, ewb, part);
  k_pick<<<dim3(16384), 256, 0, stream>>>(part, zf, ew, idxF, lprt);
  k_scalars<<<1, 256, 0, stream>>>(idxF, lprt, out);
  k_zq_out<<<dim3(8, 32, 16), 256, 0, stream>>>(z, ew, idxF, out);
  k_onehot<<<dim3(16384), 256, 0, stream>>>(idxF, out);
}

// Round 7
// 923.579 us; speedup vs baseline: 1.7765x; 1.1634x over previous
//
#include <hip/hip_runtime.h>
#include <hip/hip_bf16.h>
#include <math.h>

#define N_ROWS 16384
#define DIM    256
#define NE     8192
#define QMARGIN 21   // ceil(eps/step)+1, step=2^-17, eps~1.5e-4

// ---- out layout (float indices) ----
// loss @0 | z_q_st @1 (4194304) | perp @4194305 | one_hot @4194306 (134217728)
// indices @138412034 (16384)
//
// ---- scratch INSIDE one_hot region (d_ws untouched), 16B-aligned ----
// SOFF = 4194308
// zf    @ SOFF+0         (4194304 f32)   z as (N,D)
// zfb   @ SOFF+4194304   (4194304 bf16)  fragment-order bf16 z
// ewb   @ SOFF+6291456   (2097152 bf16)  fragment-order bf16 codebook
// part  @ SOFF+7340032   (524288 i32)    per row: 8 byc x 2 wn x (k1,k2)
// lprt  @ SOFF+7864320   (16384 f32)
// ends @ out[12075012] << 138412034; k_onehot overwrites last.
#define SOFF 4194308

typedef __bf16 bf16x8 __attribute__((ext_vector_type(8)));
typedef float  f32x4  __attribute__((ext_vector_type(4)));
typedef float  vf4    __attribute__((ext_vector_type(4)));

__device__ __forceinline__ void gload_lds16(const __bf16* g, __bf16* l) {
  __builtin_amdgcn_global_load_lds(
      (const __attribute__((address_space(1))) unsigned int*)g,
      (__attribute__((address_space(3))) unsigned int*)l, 16, 0, 0);
}

// ---------- kernel 1: transpose z -> zf (N,D) fp32 AND zfb fragment bf16 ----------
__global__ void k_prep(const float* __restrict__ z, float* __restrict__ zf,
                       __bf16* __restrict__ zfb) {
  __shared__ float tile[32][33];
  int ct = blockIdx.x, ht = blockIdx.y, b = blockIdx.z;
  int tx = threadIdx.x & 31, ty = threadIdx.x >> 5;
  int c0 = ct * 32, hw0 = ht * 32;
  const size_t zb = (size_t)b * 256 * 1024;
#pragma unroll
  for (int p = 0; p < 4; ++p) {
    int c = p * 8 + ty;
    tile[c][tx] = z[zb + (size_t)(c0 + c) * 1024 + hw0 + tx];
  }
  __syncthreads();
#pragma unroll
  for (int p = 0; p < 4; ++p) {
    int r = p * 8 + ty;
    zf[(size_t)(b * 1024 + hw0 + r) * DIM + c0 + tx] = tile[tx][r];
  }
  if (threadIdx.x < 128) {
    int r = threadIdx.x >> 2, kc = threadIdx.x & 3;
    int row = b * 1024 + hw0 + r;
    bf16x8 v;
#pragma unroll
    for (int j = 0; j < 8; ++j) v[j] = (__bf16)tile[kc * 8 + j][r];
    int tn = row >> 7, g = (row >> 4) & 7, m15 = row & 15, kt = c0 >> 5;
    *(bf16x8*)(zfb + (size_t)tn * 32768 + kt * 4096 + g * 512 + (kc * 16 + m15) * 8) = v;
  }
}

// ---------- kernel 2: codebook fp32 -> bf16 fragment order ----------
__global__ void k_cvt_e(const float* __restrict__ ew, __bf16* __restrict__ ewb) {
  int gid = blockIdx.x * 256 + threadIdx.x;  // 0..262143
  int r = gid >> 5, kc8 = gid & 31;
  const float* s = ew + (size_t)r * DIM + kc8 * 8;
  float4 v0 = *(const float4*)s, v1 = *(const float4*)(s + 4);
  bf16x8 v = {(__bf16)v0.x, (__bf16)v0.y, (__bf16)v0.z, (__bf16)v0.w,
              (__bf16)v1.x, (__bf16)v1.y, (__bf16)v1.z, (__bf16)v1.w};
  int t = r >> 7, g = (r >> 4) & 7, m15 = r & 15, kt = kc8 >> 2, kc = kc8 & 3;
  *(bf16x8*)(ewb + (size_t)t * 32768 + kt * 4096 + g * 512 + (kc * 16 + m15) * 8) = v;
}

// ---------- kernel 3: persistent-A MFMA scores, running reg top-2, 1 shfl merge ----------
__global__ __launch_bounds__(256, 2) void k_score(const __bf16* __restrict__ zfb,
                                                  const __bf16* __restrict__ ewb,
                                                  int2* __restrict__ part2) {
  __shared__ __align__(16) __bf16 Afull[32768];   // 64 KB: full 128x256 A tile
  __shared__ __align__(16) __bf16 Bs[2][4096];    // 2 x 8 KB B tiles
  const int tid = threadIdx.x;
  const int lane = tid & 63, wave = tid >> 6;
  const int wm = wave >> 1, wn = wave & 1;
  const int quad = lane >> 4, l15 = lane & 15;
  const int bx = blockIdx.x, byc = blockIdx.y;
  const __bf16* Ag = zfb + (size_t)bx * 32768;
  const __bf16* Bg = ewb + (size_t)byc * 262144;

  // stage A once (16 KB per wave)
  {
    const int base = wave * 8192;
#pragma unroll
    for (int i = 0; i < 16; ++i)
      gload_lds16(Ag + base + i * 512 + lane * 8, Afull + base + i * 512);
  }
  // prefetch B for iter 0
  {
    const int boff = wave * 1024;
    gload_lds16(Bg + boff + lane * 8, Bs[0] + boff);
    gload_lds16(Bg + boff + 512 + lane * 8, Bs[0] + boff + 512);
  }

  f32x4 acc[4][4];
#pragma unroll
  for (int i = 0; i < 4; ++i)
#pragma unroll
    for (int j = 0; j < 4; ++j) acc[i][j] = (f32x4){0.f, 0.f, 0.f, 0.f};
  int r1[16], r2[16];
#pragma unroll
  for (int i = 0; i < 16; ++i) { r1[i] = 0x7fffffff; r2[i] = 0x7fffffff; }

  for (int it = 0; it < 64; ++it) {
    const int bt = it >> 3, kt = it & 7, buf = it & 1;
    __syncthreads();
    if (it < 63) {
      const int nx = it + 1;
      const __bf16* src = Bg + (nx >> 3) * 32768 + (nx & 7) * 4096 + wave * 1024;
      gload_lds16(src + lane * 8, Bs[buf ^ 1] + wave * 1024);
      gload_lds16(src + 512 + lane * 8, Bs[buf ^ 1] + wave * 1024 + 512);
    }
    bf16x8 af[4], bfr[4];
#pragma unroll
    for (int mi = 0; mi < 4; ++mi)
      af[mi] = *(const bf16x8*)(Afull + kt * 4096 + (wm * 4 + mi) * 512 + lane * 8);
#pragma unroll
    for (int ni = 0; ni < 4; ++ni)
      bfr[ni] = *(const bf16x8*)(Bs[buf] + (wn * 4 + ni) * 512 + lane * 8);
#pragma unroll
    for (int mi = 0; mi < 4; ++mi)
#pragma unroll
      for (int ni = 0; ni < 4; ++ni)
        acc[mi][ni] = __builtin_amdgcn_mfma_f32_16x16x32_bf16(af[mi], bfr[ni],
                                                              acc[mi][ni], 0, 0, 0);
    if (kt == 7) {
      const int colb = byc * 1024 + bt * 128 + wn * 64;
#pragma unroll
      for (int mi = 0; mi < 4; ++mi) {
#pragma unroll
        for (int rg = 0; rg < 4; ++rg) {
          const int idx = mi * 4 + rg;
          float s0 = -2.f * acc[mi][0][rg], s1 = -2.f * acc[mi][1][rg];
          float s2 = -2.f * acc[mi][2][rg], s3 = -2.f * acc[mi][3][rg];
          int q0 = min(max((int)((s0 + 1.0f) * 131072.0f), 0), 262143);
          int q1 = min(max((int)((s1 + 1.0f) * 131072.0f), 0), 262143);
          int q2 = min(max((int)((s2 + 1.0f) * 131072.0f), 0), 262143);
          int q3 = min(max((int)((s3 + 1.0f) * 131072.0f), 0), 262143);
          int k0 = (q0 << 13) | (colb + l15);
          int k1 = (q1 << 13) | (colb + 16 + l15);
          int k2 = (q2 << 13) | (colb + 32 + l15);
          int k3 = (q3 << 13) | (colb + 48 + l15);
          int a = min(k0, k1), bb = max(k0, k1);
          int c = min(k2, k3), dd = max(k2, k3);
          int t1 = min(a, c);
          int t2 = min(max(a, c), min(bb, dd));
          int n1 = min(r1[idx], t1);
          int n2 = min(max(r1[idx], t1), min(r2[idx], t2));
          r1[idx] = n1; r2[idx] = n2;
        }
      }
#pragma unroll
      for (int i = 0; i < 4; ++i)
#pragma unroll
        for (int j = 0; j < 4; ++j) acc[i][j] = (f32x4){0.f, 0.f, 0.f, 0.f};
    }
  }

  // single final 16-lane lex merge + store
#pragma unroll
  for (int mi = 0; mi < 4; ++mi) {
#pragma unroll
    for (int rg = 0; rg < 4; ++rg) {
      const int idx = mi * 4 + rg;
      int k1 = r1[idx], k2 = r2[idx];
#pragma unroll
      for (int d = 1; d < 16; d <<= 1) {
        int o1 = __shfl_xor(k1, d), o2 = __shfl_xor(k2, d);
        k2 = min(max(k1, o1), min(k2, o2));
        k1 = min(k1, o1);
      }
      if (l15 == 0) {
        int row = bx * 128 + wm * 64 + mi * 16 + quad * 4 + rg;
        int2 v; v.x = k1; v.y = k2;
        part2[row * 16 + byc * 2 + wn] = v;
      }
    }
  }
}

// ---------- numpy-pairwise-exact sum of squares over 128 ----------
__device__ __forceinline__ float np_sumsq_128(const float* __restrict__ p) {
  float r[8];
#pragma unroll
  for (int j = 0; j < 8; ++j) r[j] = __fmul_rn(p[j], p[j]);
  for (int i = 8; i < 128; i += 8) {
#pragma unroll
    for (int j = 0; j < 8; ++j) r[j] = __fadd_rn(r[j], __fmul_rn(p[i + j], p[i + j]));
  }
  return __fadd_rn(__fadd_rn(__fadd_rn(r[0], r[1]), __fadd_rn(r[2], r[3])),
                   __fadd_rn(__fadd_rn(r[4], r[5]), __fadd_rn(r[6], r[7])));
}

// ---------- kernel 4: wave-per-row candidate filter + exact fp32 rescore ----------
__global__ __launch_bounds__(256) void k_pick(const int2* __restrict__ part2,
                                              const float* __restrict__ zf,
                                              const float* __restrict__ ew,
                                              float* __restrict__ idxF,
                                              float* __restrict__ losspart) {
  __shared__ int cand[4][40];
  __shared__ int cnts[4];
  const int t = threadIdx.x, lane = t & 63, wv = t >> 6;
  const int row = blockIdx.x * 4 + wv;
  if (lane == 0) cnts[wv] = 0;
  int2 pv;
  if (lane < 16) pv = part2[row * 16 + lane];
  else { pv.x = 0x7fffffff; pv.y = 0x7fffffff; }
  int kmin = pv.x;
#pragma unroll
  for (int d = 1; d < 64; d <<= 1) kmin = min(kmin, __shfl_xor(kmin, d));
  const int qthr = min((kmin >> 13) + QMARGIN, 262143);
  const int kthr = (qthr << 13) | 8191;
  __syncthreads();
  if (lane < 16) {
    if (pv.x <= kthr) { int p = atomicAdd(&cnts[wv], 1); cand[wv][p] = pv.x & 8191; }
    if (pv.y <= kthr) { int p = atomicAdd(&cnts[wv], 1); cand[wv][p] = pv.y & 8191; }
  }
  __syncthreads();
  const int cnt = cnts[wv];
  const float* zr = zf + (size_t)row * DIM;
  float bd = INFINITY; int bj = 0x7fffffff;
  if (lane < cnt) {
    int j = cand[wv][lane];
    const float* e = ew + (size_t)j * DIM;
    float acc = 0.f;
    for (int k = 0; k < DIM; ++k) acc = __builtin_fmaf(zr[k], e[k], acc);  // round-3 order
    float esq = __fadd_rn(np_sumsq_128(e), np_sumsq_128(e + 128));
    float zsq = __fadd_rn(np_sumsq_128(zr), np_sumsq_128(zr + 128));
    bd = __fsub_rn(__fadd_rn(zsq, esq), __fmul_rn(2.0f, acc));
    bj = j;
  }
#pragma unroll
  for (int d = 1; d < 64; d <<= 1) {
    float od = __shfl_xor(bd, d); int oj = __shfl_xor(bj, d);
    if (od < bd || (od == bd && oj < bj)) { bd = od; bj = oj; }
  }
  // loss partial (round-3 k_merge numerics)
  int c = lane * 4;
  float4 e4 = *reinterpret_cast<const float4*>(ew + (size_t)bj * DIM + c);
  float4 z4 = *reinterpret_cast<const float4*>(zr + c);
  float t0 = __fsub_rn(e4.x, z4.x), t1 = __fsub_rn(e4.y, z4.y);
  float t2 = __fsub_rn(e4.z, z4.z), t3 = __fsub_rn(e4.w, z4.w);
  float s = __fadd_rn(__fadd_rn(__fmul_rn(t0, t0), __fmul_rn(t1, t1)),
                      __fadd_rn(__fmul_rn(t2, t2), __fmul_rn(t3, t3)));
#pragma unroll
  for (int d = 1; d < 64; d <<= 1) s += __shfl_xor(s, d);
  if (lane == 0) {
    idxF[row] = (float)bj;
    losspart[row] = s;
  }
}

// ---------- kernel 5: loss + perplexity ----------
__global__ __launch_bounds__(256) void k_scalars(const float* __restrict__ idxF,
                                                 const float* __restrict__ losspart,
                                                 float* __restrict__ out) {
  __shared__ int hist[NE];
  __shared__ float red[256];
  int t = threadIdx.x;
  for (int i = t; i < NE; i += 256) hist[i] = 0;
  __syncthreads();
  float ls = 0.f;
  for (int i = t; i < N_ROWS; i += 256) {
    atomicAdd(&hist[(int)idxF[i]], 1);
    ls += losspart[i];
  }
  __syncthreads();
  float es = 0.f;
  for (int i = t; i < NE; i += 256) {
    float p = (float)hist[i] * (1.0f / 16384.0f);
    es += p * logf(p + 1e-10f);
  }
  red[t] = es; __syncthreads();
  for (int w = 128; w > 0; w >>= 1) { if (t < w) red[t] += red[t + w]; __syncthreads(); }
  float esum = red[0]; __syncthreads();
  red[t] = ls; __syncthreads();
  for (int w = 128; w > 0; w >>= 1) { if (t < w) red[t] += red[t + w]; __syncthreads(); }
  if (t == 0) {
    out[4194305] = expf(-esum);
    float m = red[0] * (1.0f / 4194304.0f);
    out[0] = __fadd_rn(m, __fmul_rn(0.25f, m));
  }
}

// ---------- kernel 6: z_q_st back to (B,C,H,W) ----------
__global__ void k_zq_out(const float* __restrict__ z, const float* __restrict__ ew,
                         const float* __restrict__ idxF, float* __restrict__ out) {
  __shared__ float tileE[32][33];
  __shared__ int sidx[32];
  int ct = blockIdx.x, ht = blockIdx.y, b = blockIdx.z;
  int tx = threadIdx.x & 31, ty = threadIdx.x >> 5;
  int c0 = ct * 32, hw0 = ht * 32;
  if (threadIdx.x < 32) sidx[threadIdx.x] = (int)idxF[b * 1024 + hw0 + threadIdx.x];
  __syncthreads();
#pragma unroll
  for (int p = 0; p < 4; ++p) {
    int r = p * 8 + ty;
    tileE[tx][r] = ew[(size_t)sidx[r] * DIM + c0 + tx];
  }
  __syncthreads();
  float* outq = out + 1;
#pragma unroll
  for (int p = 0; p < 4; ++p) {
    int cl = p * 8 + ty;
    size_t gi = (size_t)(b * 256 + c0 + cl) * 1024 + hw0 + tx;
    float zv = z[gi];
    outq[gi] = __fadd_rn(zv, __fsub_rn(tileE[cl][tx], zv));
  }
}

// ---------- kernel 7 (LAST): one_hot, ext-vector NT stores ----------
__global__ void k_onehot(const float* __restrict__ idxF, float* __restrict__ out) {
  int row = blockIdx.x;
  int t = threadIdx.x;
  int idx = (int)idxF[row];
  float* p = out + 4194306 + (size_t)row * NE;
  if (t == 0) {
    float2 h; h.x = (0 == idx) ? 1.f : 0.f; h.y = (1 == idx) ? 1.f : 0.f;
    *(float2*)p = h;
    float2 q; q.x = (8190 == idx) ? 1.f : 0.f; q.y = (8191 == idx) ? 1.f : 0.f;
    *(float2*)(p + 8190) = q;
  }
  vf4* b4 = (vf4*)(p + 2);
#pragma unroll
  for (int it = 0; it < 8; ++it) {
    int i = it * 256 + t;
    if (i < 2047) {
      int c = 2 + i * 4;
      vf4 v;
      v.x = (c     == idx) ? 1.f : 0.f;
      v.y = (c + 1 == idx) ? 1.f : 0.f;
      v.z = (c + 2 == idx) ? 1.f : 0.f;
      v.w = (c + 3 == idx) ? 1.f : 0.f;
      __builtin_nontemporal_store(v, b4 + i);
    }
  }
}

extern "C" void kernel_launch(void* const* d_in, const int* in_sizes, int n_in,
                              void* d_out, int out_size, void* d_ws, size_t ws_size,
                              hipStream_t stream) {
  const float* z  = (const float*)d_in[0];
  const float* ew = (const float*)d_in[1];
  float* out = (float*)d_out;
  float*  zf    = out + SOFF;
  __bf16* zfb   = (__bf16*)(out + SOFF + 4194304);
  __bf16* ewb   = (__bf16*)(out + SOFF + 6291456);
  int2*   part2 = (int2*)(out + SOFF + 7340032);
  float*  lprt  = out + SOFF + 7864320;
  float*  idxF  = out + 138412034;

  k_prep<<<dim3(8, 32, 16), 256, 0, stream>>>(z, zf, zfb);
  k_cvt_e<<<dim3(1024), 256, 0, stream>>>(ew, ewb);
  k_score<<<dim3(128, 8), 256, 0, stream>>>(zfb, ewb, part2);
  k_pick<<<dim3(4096), 256, 0, stream>>>(part2, zf, ew, idxF, lprt);
  k_scalars<<<1, 256, 0, stream>>>(idxF, lprt, out);
  k_zq_out<<<dim3(8, 32, 16), 256, 0, stream>>>(z, ew, idxF, out);
  k_onehot<<<dim3(16384), 256, 0, stream>>>(idxF, out);
}